// Round 1
// baseline (556.338 us; speedup 1.0000x reference)
//
#include <hip/hip_runtime.h>
#include <hip/hip_bf16.h>
#include <math.h>

#define NB 16          // batch
#define NC 256         // channels
#define NPTS 1000      // P*K points per batch
#define NN2 2000       // P*K*2
#define D1 1024        // FC1 hidden
#define KFLAT 16384    // C*64

// ---------------- kernel 1: 4x4 avg pool p4 (16,256,32,32) -> flat (16,16384)
__global__ __launch_bounds__(256) void k_pool(const float* __restrict__ p4,
                                              float* __restrict__ flat) {
    int o = blockIdx.x * 256 + threadIdx.x;     // [0, 16*16384)
    int bc = o >> 6;                            // b*256 + c
    int ij = o & 63;
    int i = ij >> 3, j = ij & 7;
    const float* src = p4 + ((size_t)bc * 32 + i * 4) * 32 + j * 4;
    float s = 0.f;
#pragma unroll
    for (int di = 0; di < 4; ++di) {
        float4 v = *reinterpret_cast<const float4*>(src + di * 32);
        s += v.x + v.y + v.z + v.w;
    }
    flat[o] = s * (1.0f / 16.0f);
}

// ---------------- kernel 2: h = relu(flat @ W1^T + b1)  (16 x 1024)
// one wave per output column n; flat tile staged in LDS
__global__ __launch_bounds__(256) void k_fc1(const float* __restrict__ flat,
                                             const float* __restrict__ W1,
                                             const float* __restrict__ b1,
                                             float* __restrict__ h) {
    __shared__ float lds[16 * 256];
    const int tid = threadIdx.x;
    const int wave = tid >> 6, lane = tid & 63;
    const int n = blockIdx.x * 4 + wave;        // [0,1024)
    float acc[16];
#pragma unroll
    for (int m = 0; m < 16; ++m) acc[m] = 0.f;
    const float4* W1r  = reinterpret_cast<const float4*>(W1 + (size_t)n * KFLAT);
    const float4* flat4 = reinterpret_cast<const float4*>(flat);
    float4* lds4 = reinterpret_cast<float4*>(lds);
    for (int kt = 0; kt < KFLAT; kt += 256) {
        __syncthreads();
#pragma unroll
        for (int r = 0; r < 4; ++r) {
            int idx4 = tid + r * 256;           // [0,1024) float4 units
            int m = idx4 >> 6, off = idx4 & 63;
            lds4[m * 64 + off] = flat4[m * (KFLAT / 4) + (kt >> 2) + off];
        }
        __syncthreads();
        float4 w = W1r[(kt >> 2) + lane];
#pragma unroll
        for (int m = 0; m < 16; ++m) {
            float4 f = lds4[m * 64 + lane];
            acc[m] += w.x * f.x + w.y * f.y + w.z * f.z + w.w * f.w;
        }
    }
#pragma unroll
    for (int m = 0; m < 16; ++m) {
        float v = acc[m];
#pragma unroll
        for (int off = 32; off > 0; off >>= 1) v += __shfl_xor(v, off, 64);
        acc[m] = v;
    }
    if (lane == 0) {
        float bias = b1[n];
#pragma unroll
        for (int m = 0; m < 16; ++m)
            h[m * D1 + n] = fmaxf(acc[m] + bias, 0.f);
    }
}

// ---------------- kernel 3: init = sigmoid(h @ W2^T + b2)  (16 x 2000)
__global__ __launch_bounds__(256) void k_fc2(const float* __restrict__ h,
                                             const float* __restrict__ W2,
                                             const float* __restrict__ b2,
                                             float* __restrict__ init_ws,
                                             float* __restrict__ out_init) {
    const int tid = threadIdx.x;
    const int wave = tid >> 6, lane = tid & 63;
    const int n = blockIdx.x * 4 + wave;        // [0,2000)
    float acc[16];
#pragma unroll
    for (int m = 0; m < 16; ++m) acc[m] = 0.f;
    const float4* W2r = reinterpret_cast<const float4*>(W2 + (size_t)n * D1);
    const float4* h4  = reinterpret_cast<const float4*>(h);
#pragma unroll
    for (int it = 0; it < 4; ++it) {
        int k4 = it * 64 + lane;                // float4 idx in row (256/row)
        float4 w = W2r[k4];
#pragma unroll
        for (int m = 0; m < 16; ++m) {
            float4 f = h4[m * 256 + k4];
            acc[m] += w.x * f.x + w.y * f.y + w.z * f.z + w.w * f.w;
        }
    }
    float bias = b2[n];
#pragma unroll
    for (int m = 0; m < 16; ++m) {
        float v = acc[m];
#pragma unroll
        for (int off = 32; off > 0; off >>= 1) v += __shfl_xor(v, off, 64);
        if (lane == 0) {
            float s = 1.f / (1.f + expf(-(v + bias)));
            init_ws[m * NN2 + n] = s;
            out_init[m * NN2 + n] = s;
        }
    }
}

// ---------------- kernel 4: bilinear sample, one block per (b,c) image
// sampled layout: bf16 [b][c][n]
__global__ __launch_bounds__(256) void k_sample(const float* __restrict__ p2,
                                                const float* __restrict__ init_ws,
                                                __hip_bfloat16* __restrict__ sampled) {
    const int bc = blockIdx.x;                  // b*256 + c
    const int b = bc >> 8;
    const float* img = p2 + (size_t)bc * (128 * 128);
    const float* ip = init_ws + b * NN2;
    for (int n = threadIdx.x; n < NPTS; n += 256) {
        float sx = ip[2 * n], sy = ip[2 * n + 1];
        float x = sx * 128.f - 0.5f;
        float y = sy * 128.f - 0.5f;
        float x0f = floorf(x), y0f = floorf(y);
        float wx = x - x0f, wy = y - y0f;
        int x0 = (int)x0f, y0 = (int)y0f;
        int x1 = x0 + 1, y1 = y0 + 1;
        bool vx0 = (x0 >= 0) && (x0 <= 127);
        bool vx1 = (x1 >= 0) && (x1 <= 127);
        bool vy0 = (y0 >= 0) && (y0 <= 127);
        bool vy1 = (y1 >= 0) && (y1 <= 127);
        int cx0 = min(max(x0, 0), 127), cx1 = min(max(x1, 0), 127);
        int cy0 = min(max(y0, 0), 127), cy1 = min(max(y1, 0), 127);
        float v00 = (vx0 && vy0) ? img[cy0 * 128 + cx0] : 0.f;
        float v10 = (vx1 && vy0) ? img[cy0 * 128 + cx1] : 0.f;
        float v01 = (vx0 && vy1) ? img[cy1 * 128 + cx0] : 0.f;
        float v11 = (vx1 && vy1) ? img[cy1 * 128 + cx1] : 0.f;
        float r = v00 * (1.f - wx) * (1.f - wy) + v10 * wx * (1.f - wy)
                + v01 * (1.f - wx) * wy + v11 * wx * wy;
        sampled[(size_t)bc * NPTS + n] = __float2bfloat16(r);
    }
}

// ---------------- kernel 5: h1 = relu(feat @ R1^T + rb1)
// per-batch GEMM M=128(j) N=1000(n) K=256(sampled) + 2 coord cols
// block: 128j x 64n tile; K-tiles of 64 staged in LDS
__global__ __launch_bounds__(256) void k_r1(const __hip_bfloat16* __restrict__ sampled,
                                            const float* __restrict__ init_ws,
                                            const float* __restrict__ R1,
                                            const float* __restrict__ rb1,
                                            float* __restrict__ h1) {
    __shared__ float As[64][128];   // [kk][j]
    __shared__ float Bs[64][64];    // [kk][n]
    const int tid = threadIdx.x;
    const int b = blockIdx.x >> 4;
    const int n0 = (blockIdx.x & 15) * 64;
    const int jt = tid & 15;        // j quad id
    const int nt = tid >> 4;        // n quad id
    float acc[8][4];
#pragma unroll
    for (int a = 0; a < 8; ++a)
#pragma unroll
        for (int m = 0; m < 4; ++m) acc[a][m] = 0.f;

    for (int k0 = 0; k0 < 256; k0 += 64) {
        __syncthreads();
        for (int idx = tid; idx < 128 * 64; idx += 256) {
            int kk = idx >> 7, r = idx & 127;   // r fastest -> conflict-free LDS writes
            As[kk][r] = R1[r * 258 + k0 + kk];
        }
        for (int idx = tid; idx < 64 * 64; idx += 256) {
            int r = idx >> 6, col = idx & 63;
            int n = n0 + col;
            Bs[r][col] = (n < NPTS)
                ? __bfloat162float(sampled[((size_t)(b * 256 + k0 + r)) * NPTS + n])
                : 0.f;
        }
        __syncthreads();
#pragma unroll 8
        for (int kk = 0; kk < 64; ++kk) {
            float4 a0 = *reinterpret_cast<const float4*>(&As[kk][jt * 4]);
            float4 a1 = *reinterpret_cast<const float4*>(&As[kk][64 + jt * 4]);
            float4 bb = *reinterpret_cast<const float4*>(&Bs[kk][nt * 4]);
            float av[8] = {a0.x, a0.y, a0.z, a0.w, a1.x, a1.y, a1.z, a1.w};
            float bv[4] = {bb.x, bb.y, bb.z, bb.w};
#pragma unroll
            for (int a = 0; a < 8; ++a)
#pragma unroll
                for (int m = 0; m < 4; ++m) acc[a][m] += av[a] * bv[m];
        }
    }
    // coord columns (K=256,257) + bias + relu + store
    float xs[4] = {0, 0, 0, 0}, ys[4] = {0, 0, 0, 0};
    int ns[4];
#pragma unroll
    for (int m = 0; m < 4; ++m) {
        int n = n0 + nt * 4 + m;
        ns[m] = n;
        if (n < NPTS) {
            xs[m] = init_ws[b * NN2 + 2 * n];
            ys[m] = init_ws[b * NN2 + 2 * n + 1];
        }
    }
#pragma unroll
    for (int a = 0; a < 8; ++a) {
        int j = (a < 4) ? (jt * 4 + a) : (64 + jt * 4 + (a - 4));
        float rx = R1[j * 258 + 256];
        float ry = R1[j * 258 + 257];
        float bj = rb1[j];
#pragma unroll
        for (int m = 0; m < 4; ++m) {
            int n = ns[m];
            if (n < NPTS) {
                float v = acc[a][m] + rx * xs[m] + ry * ys[m] + bj;
                h1[((size_t)(b * NPTS + n)) * 128 + j] = fmaxf(v, 0.f);
            }
        }
    }
}

// ---------------- kernel 6: h2 = relu(h1@R2^T+rb2); disp = tanh(h2@R3^T+rb3);
// refined = clip(init + 0.1*disp). one point per wave-iteration.
__global__ __launch_bounds__(256) void k_r23(const float* __restrict__ h1,
                                             const float* __restrict__ init_ws,
                                             const float* __restrict__ R2,
                                             const float* __restrict__ rb2,
                                             const float* __restrict__ R3,
                                             const float* __restrict__ rb3,
                                             float* __restrict__ refined) {
    __shared__ float R2t[128][64];  // [k][j]
    __shared__ float r3[2][64];
    __shared__ float rb2s[64];
    __shared__ float hbuf[4][128];
    const int tid = threadIdx.x, wave = tid >> 6, lane = tid & 63;
    for (int idx = tid; idx < 64 * 128; idx += 256) {
        int j = idx & 63, k = idx >> 6;
        R2t[k][j] = R2[j * 128 + k];
    }
    if (tid < 128) r3[tid >> 6][tid & 63] = R3[tid];
    if (tid < 64) rb2s[tid] = rb2[tid];
    __syncthreads();
    const float b30 = rb3[0], b31 = rb3[1];
    const int wgid = blockIdx.x * 4 + wave;     // [0,1000) = point n
    for (int it = 0; it < 16; ++it) {           // it = batch b
        int pt = wgid + it * 1000;
        __syncthreads();
        hbuf[wave][lane] = h1[(size_t)pt * 128 + lane];
        hbuf[wave][64 + lane] = h1[(size_t)pt * 128 + 64 + lane];
        __syncthreads();
        float a = rb2s[lane];
#pragma unroll 16
        for (int k = 0; k < 128; ++k)
            a += R2t[k][lane] * hbuf[wave][k];
        a = fmaxf(a, 0.f);
        float d0 = r3[0][lane] * a;
        float d1 = r3[1][lane] * a;
#pragma unroll
        for (int off = 32; off > 0; off >>= 1) {
            d0 += __shfl_xor(d0, off, 64);
            d1 += __shfl_xor(d1, off, 64);
        }
        if (lane == 0) {
            float ix = init_ws[it * NN2 + 2 * wgid];
            float iy = init_ws[it * NN2 + 2 * wgid + 1];
            float rx = ix + 0.1f * tanhf(d0 + b30);
            float ry = iy + 0.1f * tanhf(d1 + b31);
            refined[(size_t)pt * 2]     = fminf(fmaxf(rx, 0.f), 1.f);
            refined[(size_t)pt * 2 + 1] = fminf(fmaxf(ry, 0.f), 1.f);
        }
    }
}

// ---------------- kernel 7: v = sigmoid(relu(pf@V1^T+vb1)@V2^T+vb2), 320 rows
__global__ __launch_bounds__(256) void k_vhead(const float* __restrict__ refined,
                                               const float* __restrict__ V1,
                                               const float* __restrict__ vb1,
                                               const float* __restrict__ V2,
                                               const float* __restrict__ vb2,
                                               float* __restrict__ vout) {
    __shared__ float V1t[100][128]; // [k][j]
    __shared__ float pf[4][100];
    const int tid = threadIdx.x, wave = tid >> 6, lane = tid & 63;
    for (int idx = tid; idx < 100 * 128; idx += 256) {
        int j = idx & 127, k = idx >> 7;
        V1t[k][j] = V1[j * 100 + k];
    }
    __syncthreads();
    const int row = blockIdx.x * 4 + wave;      // [0,320)
    const float* src = refined + row * 100;
    if (lane < 50) {
        pf[wave][lane] = src[lane];
        pf[wave][lane + 50] = src[lane + 50];
    }
    __syncthreads();
    float a0 = vb1[lane], a1 = vb1[64 + lane];
#pragma unroll 10
    for (int k = 0; k < 100; ++k) {
        float p = pf[wave][k];
        a0 += V1t[k][lane] * p;
        a1 += V1t[k][64 + lane] * p;
    }
    float s = fmaxf(a0, 0.f) * V2[lane] + fmaxf(a1, 0.f) * V2[64 + lane];
#pragma unroll
    for (int off = 32; off > 0; off >>= 1) s += __shfl_xor(s, off, 64);
    if (lane == 0) vout[row] = 1.f / (1.f + expf(-(s + vb2[0])));
}

extern "C" void kernel_launch(void* const* d_in, const int* in_sizes, int n_in,
                              void* d_out, int out_size, void* d_ws, size_t ws_size,
                              hipStream_t stream) {
    const float* p4  = (const float*)d_in[0];
    const float* p2  = (const float*)d_in[1];
    // d_in[2] segmentation is unused by the reference
    const float* W1  = (const float*)d_in[3];
    const float* b1  = (const float*)d_in[4];
    const float* W2  = (const float*)d_in[5];
    const float* b2  = (const float*)d_in[6];
    const float* R1  = (const float*)d_in[7];
    const float* rb1 = (const float*)d_in[8];
    const float* R2  = (const float*)d_in[9];
    const float* rb2 = (const float*)d_in[10];
    const float* R3  = (const float*)d_in[11];
    const float* rb3 = (const float*)d_in[12];
    const float* V1  = (const float*)d_in[13];
    const float* vb1 = (const float*)d_in[14];
    const float* V2  = (const float*)d_in[15];
    const float* vb2 = (const float*)d_in[16];
    float* out = (float*)d_out;   // [refined 32000][v 320][init 32000]

    char* ws = (char*)d_ws;
    float* flat = (float*)(ws + 0);                     // 1,048,576 B
    float* h    = (float*)(ws + 1048576);               //    65,536 B
    float* ipts = (float*)(ws + 1114112);               //   128,000 B
    float* h1   = (float*)(ws + 1242112);               // 8,192,000 B
    __hip_bfloat16* samp = (__hip_bfloat16*)(ws + 9434112); // 8,192,000 B

    k_pool<<<1024, 256, 0, stream>>>(p4, flat);
    k_fc1<<<256, 256, 0, stream>>>(flat, W1, b1, h);
    k_fc2<<<500, 256, 0, stream>>>(h, W2, b2, ipts, out + 32320);
    k_sample<<<4096, 256, 0, stream>>>(p2, ipts, samp);
    k_r1<<<256, 256, 0, stream>>>(samp, ipts, R1, rb1, h1);
    k_r23<<<250, 256, 0, stream>>>(h1, ipts, R2, rb2, R3, rb3, out);
    k_vhead<<<80, 256, 0, stream>>>(out, V1, vb1, V2, vb2, out + 32000);
}